// Round 1
// baseline (686.413 us; speedup 1.0000x reference)
//
#include <hip/hip_runtime.h>
#include <hip/hip_bf16.h>

// GraphSAGE 2-layer, fp32.
//   L1: h   = relu(mean_agg(x) @ W1l + b1 + x @ W1r)          [100000 x 256]
//   L2: out = mean_agg(h @ W2l) + b2 + h @ W2r                [100000 x 40]
// (mean_agg commutes with the linear map, so we scatter 40-dim y2 = h@W2l
//  instead of 256-dim h: 128 MB of edge traffic instead of 819 MB.)
//
// Edge aggregation via per-call CSR build (degree -> scan -> fill), then
// node-parallel gather-sum (no float atomics).

#define NN 100000
#define NE 800000
#define NB1 391        // ceil(NN/256)

// ---------------------------------------------------------------- CSR build
__global__ __launch_bounds__(256) void k_degree(const int* __restrict__ dst,
                                                int* __restrict__ deg) {
    int e = blockIdx.x * 256 + threadIdx.x;
    if (e < NE) atomicAdd(&deg[dst[e]], 1);
}

__global__ __launch_bounds__(256) void k_scan1(const int* __restrict__ deg,
                                               int* __restrict__ rp,
                                               int* __restrict__ bsum) {
    __shared__ int s[256];
    int t = threadIdx.x;
    int i = blockIdx.x * 256 + t;
    int v = (i < NN) ? deg[i] : 0;
    s[t] = v;
    __syncthreads();
    for (int off = 1; off < 256; off <<= 1) {
        int add = (t >= off) ? s[t - off] : 0;
        __syncthreads();
        s[t] += add;
        __syncthreads();
    }
    if (i < NN) rp[i] = s[t] - v;               // block-local exclusive
    if (t == 255) bsum[blockIdx.x] = s[255];
}

__global__ __launch_bounds__(512) void k_scan2(int* __restrict__ bsum) {
    __shared__ int s[512];
    int t = threadIdx.x;
    int v = (t < NB1) ? bsum[t] : 0;
    s[t] = v;
    __syncthreads();
    for (int off = 1; off < 512; off <<= 1) {
        int add = (t >= off) ? s[t - off] : 0;
        __syncthreads();
        s[t] += add;
        __syncthreads();
    }
    if (t < NB1) bsum[t] = s[t] - v;            // exclusive block offsets
}

__global__ __launch_bounds__(256) void k_scan3(int* __restrict__ rp,
                                               const int* __restrict__ bsum,
                                               int* __restrict__ cur) {
    int i = blockIdx.x * 256 + threadIdx.x;
    if (i < NN) {
        int v = rp[i] + bsum[blockIdx.x];
        rp[i] = v;
        cur[i] = v;
    }
    if (i == 0) rp[NN] = NE;
}

__global__ __launch_bounds__(256) void k_fill(const int* __restrict__ src,
                                              const int* __restrict__ dst,
                                              int* __restrict__ cur,
                                              int* __restrict__ col) {
    int e = blockIdx.x * 256 + threadIdx.x;
    if (e < NE) {
        int d = dst[e];
        int pos = atomicAdd(&cur[d], 1);
        col[pos] = src[e];
    }
}

// ------------------------------------------------------- mean aggregation
// One wave per node; 128 dims -> float2 per lane. Output pre-normalized.
__global__ __launch_bounds__(256) void k_agg1(const int* __restrict__ rp,
                                              const int* __restrict__ col,
                                              const float* __restrict__ x,
                                              float* __restrict__ aggn) {
    int node = blockIdx.x * 4 + (threadIdx.x >> 6);
    int lane = threadIdx.x & 63;
    if (node >= NN) return;
    int beg = rp[node], end = rp[node + 1];
    float2 acc = make_float2(0.f, 0.f);
    for (int j = beg; j < end; ++j) {
        int s = col[j];                         // wave-uniform -> s_load
        float2 v = *(const float2*)&x[(size_t)s * 128 + lane * 2];
        acc.x += v.x;
        acc.y += v.y;
    }
    float inv = 1.0f / fmaxf((float)(end - beg), 1.0f);
    acc.x *= inv;
    acc.y *= inv;
    *(float2*)&aggn[(size_t)node * 128 + lane * 2] = acc;
}

// 40-dim version (y2 = h@W2l rows), lanes 0..39 active.
__global__ __launch_bounds__(256) void k_agg2(const int* __restrict__ rp,
                                              const int* __restrict__ col,
                                              const float* __restrict__ y2,
                                              float* __restrict__ aggn) {
    int node = blockIdx.x * 4 + (threadIdx.x >> 6);
    int lane = threadIdx.x & 63;
    if (node >= NN) return;
    int beg = rp[node], end = rp[node + 1];
    float acc = 0.f;
    for (int j = beg; j < end; ++j) {
        int s = col[j];
        if (lane < 40) acc += y2[(size_t)s * 40 + lane];
    }
    if (lane < 40) {
        float inv = 1.0f / fmaxf((float)(end - beg), 1.0f);
        aggn[(size_t)node * 40 + lane] = acc * inv;
    }
}

// ------------------------------------------------------------- layer-1 GEMM
// h = relu(agg1n @ W1l + x @ W1r + b1); M=100000, K=128 (x2 passes), N=256.
// 128x128 tile, 16x16 threads, 8x8 microtile, KT=16.
__global__ __launch_bounds__(256) void k_gemm1(const float* __restrict__ agg1n,
                                               const float* __restrict__ xin,
                                               const float* __restrict__ W1l,
                                               const float* __restrict__ W1r,
                                               const float* __restrict__ bias,
                                               float* __restrict__ hout) {
    __shared__ __align__(16) float As[16][132];   // [k][row], pad 132 (bank +4/k)
    __shared__ __align__(16) float Bs[16][128];   // [k][col]

    const int tid = threadIdx.x;
    const int tx = tid & 15, ty = tid >> 4;
    const int m0 = blockIdx.x * 128;
    const int n0 = blockIdx.y * 128;

    float acc[8][8] = {};

    for (int phase = 0; phase < 2; ++phase) {
        const float* A = phase ? xin : agg1n;
        const float* B = phase ? W1r : W1l;
        for (int kt = 0; kt < 128; kt += 16) {
            // A tile: 128 rows x 16 k  (512 float4, 2 per thread)
#pragma unroll
            for (int l = 0; l < 2; ++l) {
                int idx = tid + l * 256;
                int kq = idx & 3, row = idx >> 2;
                int gr = m0 + row;
                float4 v = make_float4(0.f, 0.f, 0.f, 0.f);
                if (gr < NN) v = *(const float4*)&A[(size_t)gr * 128 + kt + kq * 4];
                As[kq * 4 + 0][row] = v.x;
                As[kq * 4 + 1][row] = v.y;
                As[kq * 4 + 2][row] = v.z;
                As[kq * 4 + 3][row] = v.w;
            }
            // B tile: 16 k x 128 cols (512 float4, 2 per thread)
#pragma unroll
            for (int l = 0; l < 2; ++l) {
                int idx = tid + l * 256;
                int c4 = idx & 31, kr = idx >> 5;
                float4 v = *(const float4*)&B[(size_t)(kt + kr) * 256 + n0 + c4 * 4];
                *(float4*)&Bs[kr][c4 * 4] = v;
            }
            __syncthreads();
#pragma unroll
            for (int k = 0; k < 16; ++k) {
                float4 a0 = *(const float4*)&As[k][ty * 8];
                float4 a1 = *(const float4*)&As[k][ty * 8 + 4];
                float4 b0 = *(const float4*)&Bs[k][tx * 8];
                float4 b1 = *(const float4*)&Bs[k][tx * 8 + 4];
                float a[8] = {a0.x, a0.y, a0.z, a0.w, a1.x, a1.y, a1.z, a1.w};
                float b[8] = {b0.x, b0.y, b0.z, b0.w, b1.x, b1.y, b1.z, b1.w};
#pragma unroll
                for (int i = 0; i < 8; ++i)
#pragma unroll
                    for (int j = 0; j < 8; ++j) acc[i][j] += a[i] * b[j];
            }
            __syncthreads();
        }
    }
    // epilogue: +bias, relu, store
    float4 bb0 = *(const float4*)&bias[n0 + tx * 8];
    float4 bb1 = *(const float4*)&bias[n0 + tx * 8 + 4];
    float bv[8] = {bb0.x, bb0.y, bb0.z, bb0.w, bb1.x, bb1.y, bb1.z, bb1.w};
#pragma unroll
    for (int i = 0; i < 8; ++i) {
        int gr = m0 + ty * 8 + i;
        if (gr >= NN) continue;
        float4 o0, o1;
        o0.x = fmaxf(acc[i][0] + bv[0], 0.f);
        o0.y = fmaxf(acc[i][1] + bv[1], 0.f);
        o0.z = fmaxf(acc[i][2] + bv[2], 0.f);
        o0.w = fmaxf(acc[i][3] + bv[3], 0.f);
        o1.x = fmaxf(acc[i][4] + bv[4], 0.f);
        o1.y = fmaxf(acc[i][5] + bv[5], 0.f);
        o1.z = fmaxf(acc[i][6] + bv[6], 0.f);
        o1.w = fmaxf(acc[i][7] + bv[7], 0.f);
        *(float4*)&hout[(size_t)gr * 256 + n0 + tx * 8] = o0;
        *(float4*)&hout[(size_t)gr * 256 + n0 + tx * 8 + 4] = o1;
    }
}

// ------------------------------------------------------------- layer-2 GEMM
// out = A @ W (+bias) (+addp);  M=100000, K=256, N=40.
// 256-row tile, thread: 4 rows x 10 cols.  W tile staged in LDS.
__global__ __launch_bounds__(256) void k_gemm2(const float* __restrict__ A,
                                               const float* __restrict__ W,
                                               const float* __restrict__ bias,
                                               const float* __restrict__ addp,
                                               float* __restrict__ out) {
    __shared__ float As[32][257];   // [k][row]
    __shared__ float Ws[32][40];    // [k][col]
    const int tid = threadIdx.x;
    const int r = tid & 63, cg = tid >> 6;      // cg in [0,4): cols cg*10..+9
    const int m0 = blockIdx.x * 256;
    float acc[4][10] = {};

    for (int kt = 0; kt < 256; kt += 32) {
        // A tile: 256 rows x 32 k (2048 float4, 8 per thread)
#pragma unroll
        for (int l = 0; l < 8; ++l) {
            int idx = tid + l * 256;
            int kq = idx & 7, row = idx >> 3;
            int gr = m0 + row;
            float4 v = make_float4(0.f, 0.f, 0.f, 0.f);
            if (gr < NN) v = *(const float4*)&A[(size_t)gr * 256 + kt + kq * 4];
            As[kq * 4 + 0][row] = v.x;
            As[kq * 4 + 1][row] = v.y;
            As[kq * 4 + 2][row] = v.z;
            As[kq * 4 + 3][row] = v.w;
        }
        // W tile: 32 k x 40 cols (1280 floats, 5 per thread)
#pragma unroll
        for (int l = 0; l < 5; ++l) {
            int idx = tid + l * 256;
            int c = idx % 40, k = idx / 40;
            Ws[k][c] = W[(size_t)(kt + k) * 40 + c];
        }
        __syncthreads();
#pragma unroll
        for (int k = 0; k < 32; ++k) {
            float a0 = As[k][r];
            float a1 = As[k][r + 64];
            float a2 = As[k][r + 128];
            float a3 = As[k][r + 192];
#pragma unroll
            for (int j = 0; j < 10; ++j) {
                float wv = Ws[k][cg * 10 + j];
                acc[0][j] += a0 * wv;
                acc[1][j] += a1 * wv;
                acc[2][j] += a2 * wv;
                acc[3][j] += a3 * wv;
            }
        }
        __syncthreads();
    }
#pragma unroll
    for (int l = 0; l < 4; ++l) {
        int gr = m0 + r + l * 64;
        if (gr >= NN) continue;
#pragma unroll
        for (int j = 0; j < 10; ++j) {
            int c = cg * 10 + j;
            float v = acc[l][j];
            if (bias) v += bias[c];
            if (addp) v += addp[(size_t)gr * 40 + c];
            out[(size_t)gr * 40 + c] = v;
        }
    }
}

// ------------------------------------------------------------------- launch
extern "C" void kernel_launch(void* const* d_in, const int* in_sizes, int n_in,
                              void* d_out, int out_size, void* d_ws, size_t ws_size,
                              hipStream_t stream) {
    const float* x   = (const float*)d_in[0];
    const int*   ei  = (const int*)d_in[1];
    const int*   src = ei;
    const int*   dst = ei + NE;
    const float* W1l = (const float*)d_in[2];
    const float* b1  = (const float*)d_in[3];
    const float* W1r = (const float*)d_in[4];
    const float* W2l = (const float*)d_in[5];
    const float* b2  = (const float*)d_in[6];
    const float* W2r = (const float*)d_in[7];
    float* out = (float*)d_out;

    size_t off = 0;
    char* base = (char*)d_ws;
    auto alloc = [&](size_t bytes) -> void* {
        void* p = base + off;
        off += (bytes + 255) & ~(size_t)255;
        return p;
    };
    int*   deg   = (int*)alloc((size_t)NN * 4);
    int*   rp    = (int*)alloc((size_t)(NN + 1) * 4);
    int*   cur   = (int*)alloc((size_t)NN * 4);
    int*   bsum  = (int*)alloc(512 * 4);
    int*   col   = (int*)alloc((size_t)NE * 4);
    float* h     = (float*)alloc((size_t)NN * 256 * 4);
    float* agg1n = (float*)alloc((size_t)NN * 128 * 4);
    float* y2    = agg1n;                 // agg1n dead after k_gemm1: reuse
    float* agg2n = agg1n + (size_t)NN * 40;

    hipMemsetAsync(deg, 0, (size_t)NN * 4, stream);
    k_degree<<<(NE + 255) / 256, 256, 0, stream>>>(dst, deg);
    k_scan1<<<NB1, 256, 0, stream>>>(deg, rp, bsum);
    k_scan2<<<1, 512, 0, stream>>>(bsum);
    k_scan3<<<NB1, 256, 0, stream>>>(rp, bsum, cur);
    k_fill<<<(NE + 255) / 256, 256, 0, stream>>>(src, dst, cur, col);

    k_agg1<<<(NN + 3) / 4, 256, 0, stream>>>(rp, col, x, agg1n);
    k_gemm1<<<dim3((NN + 127) / 128, 2), 256, 0, stream>>>(agg1n, x, W1l, W1r, b1, h);
    k_gemm2<<<(NN + 255) / 256, 256, 0, stream>>>(h, W2l, nullptr, nullptr, y2);
    k_agg2<<<(NN + 3) / 4, 256, 0, stream>>>(rp, col, y2, agg2n);
    k_gemm2<<<(NN + 255) / 256, 256, 0, stream>>>(h, W2r, b2, agg2n, out);
}

// Round 2
// 374.838 us; speedup vs baseline: 1.8312x; 1.8312x over previous
//
#include <hip/hip_runtime.h>
#include <hip/hip_bf16.h>

// GraphSAGE 2-layer, bf16 MFMA version.
//   L1: h   = relu([agg1|x] @ [W1l;W1r] + b1)   K=256, N=256, bf16 MFMA
//   L2: [y2|t] = h @ [W2l|W2r] (+b2 on t)       K=256, N=80,  bf16 MFMA
//   out = mean_gather(y2) + t
// All M-dim buffers padded to 100096 rows -> no bounds checks in GEMMs.

#define NN   100000
#define NNP  100096          // 782*128 = 391*256
#define NE   800000
#define NB1  391             // ceil(NN/256)

typedef unsigned short ushortT;
typedef __attribute__((ext_vector_type(8))) short bf16x8;
typedef __attribute__((ext_vector_type(4))) float f32x4;

__device__ __forceinline__ unsigned short f2b(float f) {
    unsigned u = __float_as_uint(f);
    return (unsigned short)((u + 0x7fffu + ((u >> 16) & 1u)) >> 16);
}
__device__ __forceinline__ float b2f(unsigned short v) {
    return __uint_as_float(((unsigned)v) << 16);
}
__device__ __forceinline__ void llds16(const unsigned short* g, unsigned short* s) {
    __builtin_amdgcn_global_load_lds(
        (const __attribute__((address_space(1))) void*)g,
        (__attribute__((address_space(3))) void*)s, 16, 0, 0);
}

// ---------------------------------------------------------------- CSR build
__global__ __launch_bounds__(256) void k_degree(const int* __restrict__ dst,
                                                int* __restrict__ deg) {
    int e = blockIdx.x * 256 + threadIdx.x;
    if (e < NE) atomicAdd(&deg[dst[e]], 1);
}

__global__ __launch_bounds__(256) void k_scan1(const int* __restrict__ deg,
                                               int* __restrict__ rp,
                                               int* __restrict__ bsum) {
    __shared__ int s[256];
    int t = threadIdx.x;
    int i = blockIdx.x * 256 + t;
    int v = (i < NN) ? deg[i] : 0;
    s[t] = v;
    __syncthreads();
    for (int off = 1; off < 256; off <<= 1) {
        int add = (t >= off) ? s[t - off] : 0;
        __syncthreads();
        s[t] += add;
        __syncthreads();
    }
    if (i < NN) rp[i] = s[t] - v;
    if (t == 255) bsum[blockIdx.x] = s[255];
}

__global__ __launch_bounds__(512) void k_scan2(int* __restrict__ bsum) {
    __shared__ int s[512];
    int t = threadIdx.x;
    int v = (t < NB1) ? bsum[t] : 0;
    s[t] = v;
    __syncthreads();
    for (int off = 1; off < 512; off <<= 1) {
        int add = (t >= off) ? s[t - off] : 0;
        __syncthreads();
        s[t] += add;
        __syncthreads();
    }
    if (t < NB1) bsum[t] = s[t] - v;
}

__global__ __launch_bounds__(256) void k_scan3(int* __restrict__ rp,
                                               const int* __restrict__ bsum,
                                               int* __restrict__ cur) {
    int i = blockIdx.x * 256 + threadIdx.x;
    if (i < NN) {
        int v = rp[i] + bsum[blockIdx.x];
        rp[i] = v;
        cur[i] = v;
    }
    if (i == 0) rp[NN] = NE;
}

__global__ __launch_bounds__(256) void k_fill(const int* __restrict__ src,
                                              const int* __restrict__ dst,
                                              int* __restrict__ cur,
                                              int* __restrict__ col) {
    int e = blockIdx.x * 256 + threadIdx.x;
    if (e < NE) {
        int d = dst[e];
        int pos = atomicAdd(&cur[d], 1);
        col[pos] = src[e];
    }
}

// ------------------------------------------------------------------- prep
// x fp32 -> bf16 into A_cat[:,128:256]
__global__ __launch_bounds__(256) void k_cast_x(const float* __restrict__ x,
                                                ushortT* __restrict__ Ac) {
    int t = blockIdx.x * 256 + threadIdx.x;       // over NN*32 float4s
    int row = t >> 5, c4 = t & 31;
    float4 v = *(const float4*)&x[(size_t)row * 128 + c4 * 4];
    ushortT* p = Ac + (size_t)row * 256 + 128 + c4 * 4;
    p[0] = f2b(v.x); p[1] = f2b(v.y); p[2] = f2b(v.z); p[3] = f2b(v.w);
}

// weights -> bf16, transposed (B^T layout [N][K])
__global__ __launch_bounds__(256) void k_prep_w(const float* __restrict__ W1l,
                                                const float* __restrict__ W1r,
                                                const float* __restrict__ W2l,
                                                const float* __restrict__ W2r,
                                                ushortT* __restrict__ WT1,
                                                ushortT* __restrict__ WT2) {
    int idx = blockIdx.x * 256 + threadIdx.x;
    if (idx < 65536) {                            // WT1 [256n][256k]
        int n = idx >> 8, k = idx & 255;
        float v = (k < 128) ? W1l[(size_t)k * 256 + n] : W1r[(size_t)(k - 128) * 256 + n];
        WT1[idx] = f2b(v);
    } else if (idx < 65536 + 20480) {             // WT2 [80n][256k]
        int j = idx - 65536;
        int n = j >> 8, k = j & 255;
        float v = (n < 40) ? W2l[(size_t)k * 40 + n] : W2r[(size_t)k * 40 + (n - 40)];
        WT2[j] = f2b(v);
    }
}

// ------------------------------------------------------- mean aggregation 1
// gather bf16 x rows (A_cat[:,128:]), write bf16 mean to A_cat[:,0:128].
// One wave per node, 2 edges per iteration (lane halves), ushort4 loads.
__global__ __launch_bounds__(256) void k_agg1(const int* __restrict__ rp,
                                              const int* __restrict__ col,
                                              ushortT* __restrict__ Ac) {
    int node = blockIdx.x * 4 + (threadIdx.x >> 6);
    int l = threadIdx.x & 63;
    if (node >= NN) return;
    int half = l >> 5, dl = l & 31;
    int beg = rp[node], end = rp[node + 1];
    float a0 = 0.f, a1 = 0.f, a2 = 0.f, a3 = 0.f;
    for (int j = beg; j < end; j += 2) {
        int e = j + half;
        if (e < end) {
            int c = col[e];
            ushort4 v = *(const ushort4*)(Ac + (size_t)c * 256 + 128 + dl * 4);
            a0 += b2f(v.x); a1 += b2f(v.y); a2 += b2f(v.z); a3 += b2f(v.w);
        }
    }
    a0 += __shfl_xor(a0, 32); a1 += __shfl_xor(a1, 32);
    a2 += __shfl_xor(a2, 32); a3 += __shfl_xor(a3, 32);
    if (half == 0) {
        float inv = 1.0f / fmaxf((float)(end - beg), 1.0f);
        ushort4 o;
        o.x = f2b(a0 * inv); o.y = f2b(a1 * inv);
        o.z = f2b(a2 * inv); o.w = f2b(a3 * inv);
        *(ushort4*)(Ac + (size_t)node * 256 + dl * 4) = o;
    }
}

// ------------------------------------------------------------- layer-1 GEMM
// h = relu(A_cat @ WT1^T + b1).  M=NNP, K=256, N=256, bf16 MFMA 16x16x32.
// Block 128 rows x 256 cols, 4 waves (2x2), wave = 64x128, BK=64.
__global__ __launch_bounds__(256) void k_gemm1(const ushortT* __restrict__ Ac,
                                               const ushortT* __restrict__ WT1,
                                               const float* __restrict__ b1,
                                               ushortT* __restrict__ h) {
    __shared__ ushortT As[128 * 64];   // 16 KB, row-major [row][64k]
    __shared__ ushortT Bs[256 * 64];   // 32 KB, [n][64k]
    const int tid = threadIdx.x, l = tid & 63, wid = tid >> 6;
    const int wm = wid & 1, wn = wid >> 1;
    const int m0 = blockIdx.x * 128;
    const int q = l >> 4, r = l & 15;

    f32x4 acc[4][8];
#pragma unroll
    for (int i = 0; i < 4; ++i)
#pragma unroll
        for (int j = 0; j < 8; ++j) acc[i][j] = (f32x4){0.f, 0.f, 0.f, 0.f};

    for (int kt = 0; kt < 256; kt += 64) {
#pragma unroll
        for (int i = 0; i < 4; ++i) {             // A: 16 issues of 1 KB
            int flat = wid * 4 + i;
            int row = flat * 8 + (l >> 3);
            llds16(Ac + (size_t)(m0 + row) * 256 + kt + (l & 7) * 8, &As[flat * 512]);
        }
#pragma unroll
        for (int i = 0; i < 8; ++i) {             // B: 32 issues of 1 KB
            int flat = wid * 8 + i;
            int row = flat * 8 + (l >> 3);
            llds16(WT1 + (size_t)row * 256 + kt + (l & 7) * 8, &Bs[flat * 512]);
        }
        __syncthreads();
#pragma unroll
        for (int ks = 0; ks < 64; ks += 32) {
            bf16x8 af[4], bfr[8];
#pragma unroll
            for (int mt = 0; mt < 4; ++mt)
                af[mt] = *(const bf16x8*)&As[(wm * 64 + mt * 16 + r) * 64 + ks + q * 8];
#pragma unroll
            for (int nt = 0; nt < 8; ++nt)
                bfr[nt] = *(const bf16x8*)&Bs[(wn * 128 + nt * 16 + r) * 64 + ks + q * 8];
#pragma unroll
            for (int mt = 0; mt < 4; ++mt)
#pragma unroll
                for (int nt = 0; nt < 8; ++nt)
                    acc[mt][nt] = __builtin_amdgcn_mfma_f32_16x16x32_bf16(
                        af[mt], bfr[nt], acc[mt][nt], 0, 0, 0);
        }
        __syncthreads();
    }
    // epilogue: +b1, relu, bf16 store (C/D: col=lane&15, row=(lane>>4)*4+reg)
#pragma unroll
    for (int mt = 0; mt < 4; ++mt) {
        int row0 = m0 + wm * 64 + mt * 16 + q * 4;
#pragma unroll
        for (int nt = 0; nt < 8; ++nt) {
            int colb = wn * 128 + nt * 16 + r;
            float bb = b1[colb];
#pragma unroll
            for (int j = 0; j < 4; ++j) {
                float v = fmaxf(acc[mt][nt][j] + bb, 0.f);
                h[(size_t)(row0 + j) * 256 + colb] = f2b(v);
            }
        }
    }
}

// ------------------------------------------------------------- layer-2 GEMM
// [y2|t] = h @ WT2^T; t += b2.  M=NNP, K=256, N=80, 4 waves x (64 rows, 80 cols).
__global__ __launch_bounds__(256) void k_gemm2(const ushortT* __restrict__ h,
                                               const ushortT* __restrict__ WT2,
                                               const float* __restrict__ b2,
                                               ushortT* __restrict__ y2,
                                               float* __restrict__ t) {
    __shared__ ushortT As[256 * 64];   // 32 KB
    __shared__ ushortT Bs[80 * 64];    // 10 KB
    const int tid = threadIdx.x, l = tid & 63, wid = tid >> 6;
    const int m0 = blockIdx.x * 256;
    const int q = l >> 4, r = l & 15;

    f32x4 acc[4][5];
#pragma unroll
    for (int i = 0; i < 4; ++i)
#pragma unroll
        for (int j = 0; j < 5; ++j) acc[i][j] = (f32x4){0.f, 0.f, 0.f, 0.f};

    for (int kt = 0; kt < 256; kt += 64) {
#pragma unroll
        for (int i = 0; i < 8; ++i) {             // A: 32 issues
            int flat = wid * 8 + i;
            int row = flat * 8 + (l >> 3);
            llds16(h + (size_t)(m0 + row) * 256 + kt + (l & 7) * 8, &As[flat * 512]);
        }
#pragma unroll
        for (int i = 0; i < 3; ++i) {             // B: 10 issues
            int flat = wid * 3 + i;
            if (flat < 10) {
                int row = flat * 8 + (l >> 3);
                llds16(WT2 + (size_t)row * 256 + kt + (l & 7) * 8, &Bs[flat * 512]);
            }
        }
        __syncthreads();
#pragma unroll
        for (int ks = 0; ks < 64; ks += 32) {
            bf16x8 af[4], bfr[5];
#pragma unroll
            for (int mt = 0; mt < 4; ++mt)
                af[mt] = *(const bf16x8*)&As[(wid * 64 + mt * 16 + r) * 64 + ks + q * 8];
#pragma unroll
            for (int nt = 0; nt < 5; ++nt)
                bfr[nt] = *(const bf16x8*)&Bs[(nt * 16 + r) * 64 + ks + q * 8];
#pragma unroll
            for (int mt = 0; mt < 4; ++mt)
#pragma unroll
                for (int nt = 0; nt < 5; ++nt)
                    acc[mt][nt] = __builtin_amdgcn_mfma_f32_16x16x32_bf16(
                        af[mt], bfr[nt], acc[mt][nt], 0, 0, 0);
        }
        __syncthreads();
    }
#pragma unroll
    for (int mt = 0; mt < 4; ++mt) {
        int row0 = m0 + wid * 64 + mt * 16 + q * 4;
#pragma unroll
        for (int nt = 0; nt < 5; ++nt) {
            int c = nt * 16 + r;
            float bb = (c >= 40) ? b2[c - 40] : 0.f;
#pragma unroll
            for (int j = 0; j < 4; ++j) {
                float v = acc[mt][nt][j];
                if (c < 40)
                    y2[(size_t)(row0 + j) * 40 + c] = f2b(v);
                else
                    t[(size_t)(row0 + j) * 40 + (c - 40)] = v + bb;
            }
        }
    }
}

// ------------------------------------------------------- mean aggregation 2
// out = mean_gather(y2 bf16) + t
__global__ __launch_bounds__(256) void k_agg2(const int* __restrict__ rp,
                                              const int* __restrict__ col,
                                              const ushortT* __restrict__ y2,
                                              const float* __restrict__ t,
                                              float* __restrict__ out) {
    int node = blockIdx.x * 4 + (threadIdx.x >> 6);
    int l = threadIdx.x & 63;
    if (node >= NN) return;
    int half = l >> 5, dl = l & 31;
    int beg = rp[node], end = rp[node + 1];
    float a0 = 0.f, a1 = 0.f;
    for (int j = beg; j < end; j += 2) {
        int e = j + half;
        if (e < end && dl < 20) {
            int c = col[e];
            ushort2 v = *(const ushort2*)(y2 + (size_t)c * 40 + dl * 2);
            a0 += b2f(v.x); a1 += b2f(v.y);
        }
    }
    a0 += __shfl_xor(a0, 32);
    a1 += __shfl_xor(a1, 32);
    if (half == 0 && dl < 20) {
        float inv = 1.0f / fmaxf((float)(end - beg), 1.0f);
        size_t o = (size_t)node * 40 + dl * 2;
        float2 tv = *(const float2*)&t[o];
        float2 ov;
        ov.x = a0 * inv + tv.x;
        ov.y = a1 * inv + tv.y;
        *(float2*)&out[o] = ov;
    }
}

// ------------------------------------------------------------------- launch
extern "C" void kernel_launch(void* const* d_in, const int* in_sizes, int n_in,
                              void* d_out, int out_size, void* d_ws, size_t ws_size,
                              hipStream_t stream) {
    const float* x   = (const float*)d_in[0];
    const int*   ei  = (const int*)d_in[1];
    const int*   src = ei;
    const int*   dst = ei + NE;
    const float* W1l = (const float*)d_in[2];
    const float* b1  = (const float*)d_in[3];
    const float* W1r = (const float*)d_in[4];
    const float* W2l = (const float*)d_in[5];
    const float* b2  = (const float*)d_in[6];
    const float* W2r = (const float*)d_in[7];
    float* out = (float*)d_out;

    size_t off = 0;
    char* base = (char*)d_ws;
    auto alloc = [&](size_t bytes) -> void* {
        void* p = base + off;
        off += (bytes + 255) & ~(size_t)255;
        return p;
    };
    int*     deg  = (int*)alloc((size_t)NN * 4);
    int*     rp   = (int*)alloc((size_t)(NN + 1) * 4);
    int*     cur  = (int*)alloc((size_t)NN * 4);
    int*     bsum = (int*)alloc(512 * 4);
    int*     col  = (int*)alloc((size_t)NE * 4);
    ushortT* Ac   = (ushortT*)alloc((size_t)NNP * 256 * 2);   // [agg|x] bf16
    ushortT* h    = (ushortT*)alloc((size_t)NNP * 256 * 2);
    ushortT* y2   = (ushortT*)alloc((size_t)NNP * 40 * 2);
    float*   t    = (float*)alloc((size_t)NNP * 40 * 4);
    ushortT* WT1  = (ushortT*)alloc(256 * 256 * 2);
    ushortT* WT2  = (ushortT*)alloc(80 * 256 * 2);

    hipMemsetAsync(deg, 0, (size_t)NN * 4, stream);
    k_degree<<<(NE + 255) / 256, 256, 0, stream>>>(dst, deg);
    k_scan1<<<NB1, 256, 0, stream>>>(deg, rp, bsum);
    k_scan2<<<1, 512, 0, stream>>>(bsum);
    k_scan3<<<NB1, 256, 0, stream>>>(rp, bsum, cur);
    k_fill<<<(NE + 255) / 256, 256, 0, stream>>>(src, dst, cur, col);

    k_cast_x<<<(NN * 32) / 256, 256, 0, stream>>>(x, Ac);
    k_prep_w<<<(65536 + 20480 + 255) / 256, 256, 0, stream>>>(W1l, W1r, W2l, W2r, WT1, WT2);

    k_agg1<<<(NN + 3) / 4, 256, 0, stream>>>(rp, col, Ac);
    k_gemm1<<<NNP / 128, 256, 0, stream>>>(Ac, WT1, b1, h);
    k_gemm2<<<NNP / 256, 256, 0, stream>>>(h, WT2, b2, y2, t);
    k_agg2<<<(NN + 3) / 4, 256, 0, stream>>>(rp, col, y2, t, out);
}

// Round 3
// 339.751 us; speedup vs baseline: 2.0203x; 1.1033x over previous
//
#include <hip/hip_runtime.h>
#include <hip/hip_bf16.h>

// GraphSAGE 2-layer, bf16 MFMA version.
//   L1: h   = relu([agg1|x] @ [W1l;W1r] + b1)   K=256, N=256, bf16 MFMA
//   L2: [y2|t] = h @ [W2l|W2r] (+b2 on t)       K=256, N=80,  bf16 MFMA
//   out = mean_gather(y2) + t
// R3: 4-edge ILP in both gather kernels; XOR bank-swizzle in both GEMMs
//     (row stride 128B == 32 banks caused 16-way conflicts on ds_read_b128).

#define NN   100000
#define NNP  100096          // 782*128 = 391*256
#define NE   800000
#define NB1  391             // ceil(NN/256)

typedef unsigned short ushortT;
typedef __attribute__((ext_vector_type(8))) short bf16x8;
typedef __attribute__((ext_vector_type(4))) float f32x4;

__device__ __forceinline__ unsigned short f2b(float f) {
    unsigned u = __float_as_uint(f);
    return (unsigned short)((u + 0x7fffu + ((u >> 16) & 1u)) >> 16);
}
__device__ __forceinline__ float b2f(unsigned short v) {
    return __uint_as_float(((unsigned)v) << 16);
}
__device__ __forceinline__ void llds16(const unsigned short* g, unsigned short* s) {
    __builtin_amdgcn_global_load_lds(
        (const __attribute__((address_space(1))) void*)g,
        (__attribute__((address_space(3))) void*)s, 16, 0, 0);
}

// ---------------------------------------------------------------- CSR build
__global__ __launch_bounds__(256) void k_degree(const int* __restrict__ dst,
                                                int* __restrict__ deg) {
    int e = blockIdx.x * 256 + threadIdx.x;
    if (e < NE) atomicAdd(&deg[dst[e]], 1);
}

__global__ __launch_bounds__(256) void k_scan1(const int* __restrict__ deg,
                                               int* __restrict__ rp,
                                               int* __restrict__ bsum) {
    __shared__ int s[256];
    int t = threadIdx.x;
    int i = blockIdx.x * 256 + t;
    int v = (i < NN) ? deg[i] : 0;
    s[t] = v;
    __syncthreads();
    for (int off = 1; off < 256; off <<= 1) {
        int add = (t >= off) ? s[t - off] : 0;
        __syncthreads();
        s[t] += add;
        __syncthreads();
    }
    if (i < NN) rp[i] = s[t] - v;
    if (t == 255) bsum[blockIdx.x] = s[255];
}

__global__ __launch_bounds__(512) void k_scan2(int* __restrict__ bsum) {
    __shared__ int s[512];
    int t = threadIdx.x;
    int v = (t < NB1) ? bsum[t] : 0;
    s[t] = v;
    __syncthreads();
    for (int off = 1; off < 512; off <<= 1) {
        int add = (t >= off) ? s[t - off] : 0;
        __syncthreads();
        s[t] += add;
        __syncthreads();
    }
    if (t < NB1) bsum[t] = s[t] - v;
}

__global__ __launch_bounds__(256) void k_scan3(int* __restrict__ rp,
                                               const int* __restrict__ bsum,
                                               int* __restrict__ cur) {
    int i = blockIdx.x * 256 + threadIdx.x;
    if (i < NN) {
        int v = rp[i] + bsum[blockIdx.x];
        rp[i] = v;
        cur[i] = v;
    }
    if (i == 0) rp[NN] = NE;
}

__global__ __launch_bounds__(256) void k_fill(const int* __restrict__ src,
                                              const int* __restrict__ dst,
                                              int* __restrict__ cur,
                                              int* __restrict__ col) {
    int e = blockIdx.x * 256 + threadIdx.x;
    if (e < NE) {
        int d = dst[e];
        int pos = atomicAdd(&cur[d], 1);
        col[pos] = src[e];
    }
}

// ------------------------------------------------------------------- prep
// x fp32 -> bf16 into A_cat[:,128:256]
__global__ __launch_bounds__(256) void k_cast_x(const float* __restrict__ x,
                                                ushortT* __restrict__ Ac) {
    int t = blockIdx.x * 256 + threadIdx.x;       // over NN*32 float4s
    int row = t >> 5, c4 = t & 31;
    float4 v = *(const float4*)&x[(size_t)row * 128 + c4 * 4];
    ushortT* p = Ac + (size_t)row * 256 + 128 + c4 * 4;
    p[0] = f2b(v.x); p[1] = f2b(v.y); p[2] = f2b(v.z); p[3] = f2b(v.w);
}

// weights -> bf16, transposed (B^T layout [N][K])
__global__ __launch_bounds__(256) void k_prep_w(const float* __restrict__ W1l,
                                                const float* __restrict__ W1r,
                                                const float* __restrict__ W2l,
                                                const float* __restrict__ W2r,
                                                ushortT* __restrict__ WT1,
                                                ushortT* __restrict__ WT2) {
    int idx = blockIdx.x * 256 + threadIdx.x;
    if (idx < 65536) {                            // WT1 [256n][256k]
        int n = idx >> 8, k = idx & 255;
        float v = (k < 128) ? W1l[(size_t)k * 256 + n] : W1r[(size_t)(k - 128) * 256 + n];
        WT1[idx] = f2b(v);
    } else if (idx < 65536 + 20480) {             // WT2 [80n][256k]
        int j = idx - 65536;
        int n = j >> 8, k = j & 255;
        float v = (n < 40) ? W2l[(size_t)k * 40 + n] : W2r[(size_t)k * 40 + (n - 40)];
        WT2[j] = f2b(v);
    }
}

// ------------------------------------------------------- mean aggregation 1
// gather bf16 x rows (A_cat[:,128:]), write bf16 mean to A_cat[:,0:128].
// One wave per node, 4 edges in flight (16 lanes x bf16x8 per edge).
__global__ __launch_bounds__(256) void k_agg1(const int* __restrict__ rp,
                                              const int* __restrict__ col,
                                              ushortT* __restrict__ Ac) {
    int node = blockIdx.x * 4 + (threadIdx.x >> 6);
    int l = threadIdx.x & 63;
    if (node >= NN) return;
    int seg = l >> 4, dl = l & 15;                // dl covers dims dl*8..dl*8+7
    int beg = rp[node], end = rp[node + 1];
    float a[8] = {0.f, 0.f, 0.f, 0.f, 0.f, 0.f, 0.f, 0.f};
    for (int j = beg; j < end; j += 4) {
        int e = j + seg;
        if (e < end) {
            int c = col[e];
            bf16x8 v = *(const bf16x8*)(Ac + (size_t)c * 256 + 128 + dl * 8);
#pragma unroll
            for (int i = 0; i < 8; ++i) a[i] += b2f((unsigned short)v[i]);
        }
    }
#pragma unroll
    for (int i = 0; i < 8; ++i) {
        a[i] += __shfl_xor(a[i], 16);
        a[i] += __shfl_xor(a[i], 32);
    }
    if (seg == 0) {
        float inv = 1.0f / fmaxf((float)(end - beg), 1.0f);
        bf16x8 o;
#pragma unroll
        for (int i = 0; i < 8; ++i) o[i] = (short)f2b(a[i] * inv);
        *(bf16x8*)(Ac + (size_t)node * 256 + dl * 8) = o;
    }
}

// ------------------------------------------------------------- layer-1 GEMM
// h = relu(A_cat @ WT1^T + b1).  M=NNP, K=256, N=256, bf16 MFMA 16x16x32.
// Block 128 rows x 256 cols, 4 waves (2x2), BK=64, XOR chunk swizzle.
__global__ __launch_bounds__(256) void k_gemm1(const ushortT* __restrict__ Ac,
                                               const ushortT* __restrict__ WT1,
                                               const float* __restrict__ b1,
                                               ushortT* __restrict__ h) {
    __shared__ ushortT As[128 * 64];   // 16 KB, [row][64k], chunk c holds k-chunk c^(row&7)
    __shared__ ushortT Bs[256 * 64];   // 32 KB
    const int tid = threadIdx.x, l = tid & 63, wid = tid >> 6;
    const int wm = wid & 1, wn = wid >> 1;
    const int m0 = blockIdx.x * 128;
    const int q = l >> 4, r = l & 15;
    const int swz = (l & 7) ^ ((l >> 3) & 7);     // staging: fetch chunk swz for row-in-8

    f32x4 acc[4][8];
#pragma unroll
    for (int i = 0; i < 4; ++i)
#pragma unroll
        for (int j = 0; j < 8; ++j) acc[i][j] = (f32x4){0.f, 0.f, 0.f, 0.f};

    for (int kt = 0; kt < 256; kt += 64) {
#pragma unroll
        for (int i = 0; i < 4; ++i) {             // A: 16 issues of 1 KB
            int flat = wid * 4 + i;
            int row = flat * 8 + (l >> 3);
            llds16(Ac + (size_t)(m0 + row) * 256 + kt + swz * 8, &As[flat * 512]);
        }
#pragma unroll
        for (int i = 0; i < 8; ++i) {             // B: 32 issues of 1 KB
            int flat = wid * 8 + i;
            int row = flat * 8 + (l >> 3);
            llds16(WT1 + (size_t)row * 256 + kt + swz * 8, &Bs[flat * 512]);
        }
        __syncthreads();
#pragma unroll
        for (int ks = 0; ks < 64; ks += 32) {
            bf16x8 af[4], bfr[8];
            const int c0 = (ks >> 3) + q;
            const int cs = (c0 ^ (r & 7)) * 8;
#pragma unroll
            for (int mt = 0; mt < 4; ++mt)
                af[mt] = *(const bf16x8*)&As[(wm * 64 + mt * 16 + r) * 64 + cs];
#pragma unroll
            for (int nt = 0; nt < 8; ++nt)
                bfr[nt] = *(const bf16x8*)&Bs[(wn * 128 + nt * 16 + r) * 64 + cs];
#pragma unroll
            for (int mt = 0; mt < 4; ++mt)
#pragma unroll
                for (int nt = 0; nt < 8; ++nt)
                    acc[mt][nt] = __builtin_amdgcn_mfma_f32_16x16x32_bf16(
                        af[mt], bfr[nt], acc[mt][nt], 0, 0, 0);
        }
        __syncthreads();
    }
    // epilogue: +b1, relu, bf16 store (C/D: col=lane&15, row=(lane>>4)*4+reg)
#pragma unroll
    for (int mt = 0; mt < 4; ++mt) {
        int row0 = m0 + wm * 64 + mt * 16 + q * 4;
#pragma unroll
        for (int nt = 0; nt < 8; ++nt) {
            int colb = wn * 128 + nt * 16 + r;
            float bb = b1[colb];
#pragma unroll
            for (int j = 0; j < 4; ++j) {
                float v = fmaxf(acc[mt][nt][j] + bb, 0.f);
                h[(size_t)(row0 + j) * 256 + colb] = f2b(v);
            }
        }
    }
}

// ------------------------------------------------------------- layer-2 GEMM
// [y2|t] = h @ WT2^T; t += b2.  M=NNP, K=256, N=80, 4 waves x (64 rows, 80 cols).
__global__ __launch_bounds__(256) void k_gemm2(const ushortT* __restrict__ h,
                                               const ushortT* __restrict__ WT2,
                                               const float* __restrict__ b2,
                                               ushortT* __restrict__ y2,
                                               float* __restrict__ t) {
    __shared__ ushortT As[256 * 64];   // 32 KB
    __shared__ ushortT Bs[80 * 64];    // 10 KB
    const int tid = threadIdx.x, l = tid & 63, wid = tid >> 6;
    const int m0 = blockIdx.x * 256;
    const int q = l >> 4, r = l & 15;
    const int swz = (l & 7) ^ ((l >> 3) & 7);

    f32x4 acc[4][5];
#pragma unroll
    for (int i = 0; i < 4; ++i)
#pragma unroll
        for (int j = 0; j < 5; ++j) acc[i][j] = (f32x4){0.f, 0.f, 0.f, 0.f};

    for (int kt = 0; kt < 256; kt += 64) {
#pragma unroll
        for (int i = 0; i < 8; ++i) {             // A: 32 issues
            int flat = wid * 8 + i;
            int row = flat * 8 + (l >> 3);
            llds16(h + (size_t)(m0 + row) * 256 + kt + swz * 8, &As[flat * 512]);
        }
#pragma unroll
        for (int i = 0; i < 3; ++i) {             // B: 10 issues
            int flat = wid * 3 + i;
            if (flat < 10) {
                int row = flat * 8 + (l >> 3);
                llds16(WT2 + (size_t)row * 256 + kt + swz * 8, &Bs[flat * 512]);
            }
        }
        __syncthreads();
#pragma unroll
        for (int ks = 0; ks < 64; ks += 32) {
            bf16x8 af[4], bfr[5];
            const int c0 = (ks >> 3) + q;
            const int cs = (c0 ^ (r & 7)) * 8;
#pragma unroll
            for (int mt = 0; mt < 4; ++mt)
                af[mt] = *(const bf16x8*)&As[(wid * 64 + mt * 16 + r) * 64 + cs];
#pragma unroll
            for (int nt = 0; nt < 5; ++nt)
                bfr[nt] = *(const bf16x8*)&Bs[(nt * 16 + r) * 64 + cs];
#pragma unroll
            for (int mt = 0; mt < 4; ++mt)
#pragma unroll
                for (int nt = 0; nt < 5; ++nt)
                    acc[mt][nt] = __builtin_amdgcn_mfma_f32_16x16x32_bf16(
                        af[mt], bfr[nt], acc[mt][nt], 0, 0, 0);
        }
        __syncthreads();
    }
#pragma unroll
    for (int mt = 0; mt < 4; ++mt) {
        int row0 = m0 + wid * 64 + mt * 16 + q * 4;
#pragma unroll
        for (int nt = 0; nt < 5; ++nt) {
            int c = nt * 16 + r;
            float bb = (c >= 40) ? b2[c - 40] : 0.f;
#pragma unroll
            for (int j = 0; j < 4; ++j) {
                float v = acc[mt][nt][j];
                if (c < 40)
                    y2[(size_t)(row0 + j) * 40 + c] = f2b(v);
                else
                    t[(size_t)(row0 + j) * 40 + (c - 40)] = v + bb;
            }
        }
    }
}

// ------------------------------------------------------- mean aggregation 2
// out = mean_gather(y2 bf16) + t ; 4 edges in flight (16 lanes x ushort4).
__global__ __launch_bounds__(256) void k_agg2(const int* __restrict__ rp,
                                              const int* __restrict__ col,
                                              const ushortT* __restrict__ y2,
                                              const float* __restrict__ t,
                                              float* __restrict__ out) {
    int node = blockIdx.x * 4 + (threadIdx.x >> 6);
    int l = threadIdx.x & 63;
    if (node >= NN) return;
    int seg = l >> 4, dl = l & 15;                // dl<10 covers dims dl*4..+3
    int beg = rp[node], end = rp[node + 1];
    bool act = dl < 10;
    float a0 = 0.f, a1 = 0.f, a2 = 0.f, a3 = 0.f;
    for (int j = beg; j < end; j += 4) {
        int e = j + seg;
        if (e < end && act) {
            int c = col[e];
            ushort4 v = *(const ushort4*)(y2 + (size_t)c * 40 + dl * 4);
            a0 += b2f(v.x); a1 += b2f(v.y); a2 += b2f(v.z); a3 += b2f(v.w);
        }
    }
    a0 += __shfl_xor(a0, 16); a0 += __shfl_xor(a0, 32);
    a1 += __shfl_xor(a1, 16); a1 += __shfl_xor(a1, 32);
    a2 += __shfl_xor(a2, 16); a2 += __shfl_xor(a2, 32);
    a3 += __shfl_xor(a3, 16); a3 += __shfl_xor(a3, 32);
    if (seg == 0 && act) {
        float inv = 1.0f / fmaxf((float)(end - beg), 1.0f);
        size_t o = (size_t)node * 40 + dl * 4;
        float4 tv = *(const float4*)&t[o];
        float4 ov;
        ov.x = a0 * inv + tv.x;
        ov.y = a1 * inv + tv.y;
        ov.z = a2 * inv + tv.z;
        ov.w = a3 * inv + tv.w;
        *(float4*)&out[o] = ov;
    }
}

// ------------------------------------------------------------------- launch
extern "C" void kernel_launch(void* const* d_in, const int* in_sizes, int n_in,
                              void* d_out, int out_size, void* d_ws, size_t ws_size,
                              hipStream_t stream) {
    const float* x   = (const float*)d_in[0];
    const int*   ei  = (const int*)d_in[1];
    const int*   src = ei;
    const int*   dst = ei + NE;
    const float* W1l = (const float*)d_in[2];
    const float* b1  = (const float*)d_in[3];
    const float* W1r = (const float*)d_in[4];
    const float* W2l = (const float*)d_in[5];
    const float* b2  = (const float*)d_in[6];
    const float* W2r = (const float*)d_in[7];
    float* out = (float*)d_out;

    size_t off = 0;
    char* base = (char*)d_ws;
    auto alloc = [&](size_t bytes) -> void* {
        void* p = base + off;
        off += (bytes + 255) & ~(size_t)255;
        return p;
    };
    int*     deg  = (int*)alloc((size_t)NN * 4);
    int*     rp   = (int*)alloc((size_t)(NN + 1) * 4);
    int*     cur  = (int*)alloc((size_t)NN * 4);
    int*     bsum = (int*)alloc(512 * 4);
    int*     col  = (int*)alloc((size_t)NE * 4);
    ushortT* Ac   = (ushortT*)alloc((size_t)NNP * 256 * 2);   // [agg|x] bf16
    ushortT* h    = (ushortT*)alloc((size_t)NNP * 256 * 2);
    ushortT* y2   = (ushortT*)alloc((size_t)NNP * 40 * 2);
    float*   t    = (float*)alloc((size_t)NNP * 40 * 4);
    ushortT* WT1  = (ushortT*)alloc(256 * 256 * 2);
    ushortT* WT2  = (ushortT*)alloc(80 * 256 * 2);

    hipMemsetAsync(deg, 0, (size_t)NN * 4, stream);
    k_degree<<<(NE + 255) / 256, 256, 0, stream>>>(dst, deg);
    k_scan1<<<NB1, 256, 0, stream>>>(deg, rp, bsum);
    k_scan2<<<1, 512, 0, stream>>>(bsum);
    k_scan3<<<NB1, 256, 0, stream>>>(rp, bsum, cur);
    k_fill<<<(NE + 255) / 256, 256, 0, stream>>>(src, dst, cur, col);

    k_cast_x<<<(NN * 32) / 256, 256, 0, stream>>>(x, Ac);
    k_prep_w<<<(65536 + 20480 + 255) / 256, 256, 0, stream>>>(W1l, W1r, W2l, W2r, WT1, WT2);

    k_agg1<<<(NN + 3) / 4, 256, 0, stream>>>(rp, col, Ac);
    k_gemm1<<<NNP / 128, 256, 0, stream>>>(Ac, WT1, b1, h);
    k_gemm2<<<NNP / 256, 256, 0, stream>>>(h, WT2, b2, y2, t);
    k_agg2<<<(NN + 3) / 4, 256, 0, stream>>>(rp, col, y2, t, out);
}

// Round 4
// 303.895 us; speedup vs baseline: 2.2587x; 1.1180x over previous
//
#include <hip/hip_runtime.h>
#include <hip/hip_bf16.h>

// GraphSAGE 2-layer, bf16 MFMA version.
//   L1: h   = relu([agg1|x] @ [W1l;W1r] + b1)   K=256, N=256, bf16 MFMA
//   L2: [y2|t] = h @ [W2l|W2r] (+b2 on t)       K=256, N=80,  bf16 MFMA
//   out = mean_gather(y2) + t
// R4: smaller wave tiles (64x64 / 32x80) -> acc AGPRs 64/40 instead of 128/80
//     (R3 gemm1 was 1 wave/SIMD: 164 VGPR + 128 AGPR unified). rank fused into
//     degree pass -> k_fill has no atomic.

#define NN   100000
#define NNP  100096          // 782*128 = 391*256
#define NE   800000
#define NB1  391             // ceil(NN/256)

typedef unsigned short ushortT;
typedef __attribute__((ext_vector_type(8))) short bf16x8;
typedef __attribute__((ext_vector_type(4))) float f32x4;

__device__ __forceinline__ unsigned short f2b(float f) {
    unsigned u = __float_as_uint(f);
    return (unsigned short)((u + 0x7fffu + ((u >> 16) & 1u)) >> 16);
}
__device__ __forceinline__ float b2f(unsigned short v) {
    return __uint_as_float(((unsigned)v) << 16);
}
__device__ __forceinline__ void llds16(const unsigned short* g, unsigned short* s) {
    __builtin_amdgcn_global_load_lds(
        (const __attribute__((address_space(1))) void*)g,
        (__attribute__((address_space(3))) void*)s, 16, 0, 0);
}

// ---------------------------------------------------------------- CSR build
// degree + per-edge rank in one pass (atomicAdd's old value == rank)
__global__ __launch_bounds__(256) void k_rank(const int* __restrict__ dst,
                                              int* __restrict__ deg,
                                              int* __restrict__ rank) {
    int e = blockIdx.x * 256 + threadIdx.x;
    if (e < NE) rank[e] = atomicAdd(&deg[dst[e]], 1);
}

__global__ __launch_bounds__(256) void k_scan1(const int* __restrict__ deg,
                                               int* __restrict__ rp,
                                               int* __restrict__ bsum) {
    __shared__ int s[256];
    int t = threadIdx.x;
    int i = blockIdx.x * 256 + t;
    int v = (i < NN) ? deg[i] : 0;
    s[t] = v;
    __syncthreads();
    for (int off = 1; off < 256; off <<= 1) {
        int add = (t >= off) ? s[t - off] : 0;
        __syncthreads();
        s[t] += add;
        __syncthreads();
    }
    if (i < NN) rp[i] = s[t] - v;
    if (t == 255) bsum[blockIdx.x] = s[255];
}

__global__ __launch_bounds__(512) void k_scan2(int* __restrict__ bsum) {
    __shared__ int s[512];
    int t = threadIdx.x;
    int v = (t < NB1) ? bsum[t] : 0;
    s[t] = v;
    __syncthreads();
    for (int off = 1; off < 512; off <<= 1) {
        int add = (t >= off) ? s[t - off] : 0;
        __syncthreads();
        s[t] += add;
        __syncthreads();
    }
    if (t < NB1) bsum[t] = s[t] - v;
}

__global__ __launch_bounds__(256) void k_scan3(int* __restrict__ rp,
                                               const int* __restrict__ bsum) {
    int i = blockIdx.x * 256 + threadIdx.x;
    if (i < NN) rp[i] += bsum[blockIdx.x];
    if (i == 0) rp[NN] = NE;
}

// no atomic: position = rp[dst] + precomputed rank
__global__ __launch_bounds__(256) void k_fill(const int* __restrict__ src,
                                              const int* __restrict__ dst,
                                              const int* __restrict__ rank,
                                              const int* __restrict__ rp,
                                              int* __restrict__ col) {
    int e = blockIdx.x * 256 + threadIdx.x;
    if (e < NE) col[rp[dst[e]] + rank[e]] = src[e];
}

// ------------------------------------------------------------------- prep
// x fp32 -> bf16 into A_cat[:,128:256]; weights -> bf16 B^T layouts
__global__ __launch_bounds__(256) void k_prep(const float* __restrict__ x,
                                              const float* __restrict__ W1l,
                                              const float* __restrict__ W1r,
                                              const float* __restrict__ W2l,
                                              const float* __restrict__ W2r,
                                              ushortT* __restrict__ Ac,
                                              ushortT* __restrict__ WT1,
                                              ushortT* __restrict__ WT2) {
    int t = blockIdx.x * 256 + threadIdx.x;       // NN*32 float4s
    int row = t >> 5, c4 = t & 31;
    float4 v = *(const float4*)&x[(size_t)row * 128 + c4 * 4];
    ushortT* p = Ac + (size_t)row * 256 + 128 + c4 * 4;
    p[0] = f2b(v.x); p[1] = f2b(v.y); p[2] = f2b(v.z); p[3] = f2b(v.w);

    if (t < 65536) {                              // WT1 [256n][256k]
        int n = t >> 8, k = t & 255;
        float w = (k < 128) ? W1l[(size_t)k * 256 + n] : W1r[(size_t)(k - 128) * 256 + n];
        WT1[t] = f2b(w);
    } else if (t < 65536 + 20480) {               // WT2 [80n][256k]
        int j = t - 65536;
        int n = j >> 8, k = j & 255;
        float w = (n < 40) ? W2l[(size_t)k * 40 + n] : W2r[(size_t)k * 40 + (n - 40)];
        WT2[j] = f2b(w);
    }
}

// ------------------------------------------------------- mean aggregation 1
// gather bf16 x rows (A_cat[:,128:]), write bf16 mean to A_cat[:,0:128].
// One wave per node, 4 edges in flight (16 lanes x bf16x8 per edge).
__global__ __launch_bounds__(256) void k_agg1(const int* __restrict__ rp,
                                              const int* __restrict__ col,
                                              ushortT* __restrict__ Ac) {
    int node = blockIdx.x * 4 + (threadIdx.x >> 6);
    int l = threadIdx.x & 63;
    if (node >= NN) return;
    int seg = l >> 4, dl = l & 15;                // dl covers dims dl*8..dl*8+7
    int beg = rp[node], end = rp[node + 1];
    float a[8] = {0.f, 0.f, 0.f, 0.f, 0.f, 0.f, 0.f, 0.f};
    for (int j = beg; j < end; j += 4) {
        int e = j + seg;
        if (e < end) {
            int c = col[e];
            bf16x8 v = *(const bf16x8*)(Ac + (size_t)c * 256 + 128 + dl * 8);
#pragma unroll
            for (int i = 0; i < 8; ++i) a[i] += b2f((unsigned short)v[i]);
        }
    }
#pragma unroll
    for (int i = 0; i < 8; ++i) {
        a[i] += __shfl_xor(a[i], 16);
        a[i] += __shfl_xor(a[i], 32);
    }
    if (seg == 0) {
        float inv = 1.0f / fmaxf((float)(end - beg), 1.0f);
        bf16x8 o;
#pragma unroll
        for (int i = 0; i < 8; ++i) o[i] = (short)f2b(a[i] * inv);
        *(bf16x8*)(Ac + (size_t)node * 256 + dl * 8) = o;
    }
}

// ------------------------------------------------------------- layer-1 GEMM
// h = relu(A_cat @ WT1^T + b1).  M=NNP, K=256, N=256.
// Block 128x128, 4 waves 2x2, wave 64x64 (acc 4x4 = 64 AGPR), BK=64.
__global__ __launch_bounds__(256, 4) void k_gemm1(const ushortT* __restrict__ Ac,
                                                  const ushortT* __restrict__ WT1,
                                                  const float* __restrict__ b1,
                                                  ushortT* __restrict__ h) {
    __shared__ ushortT As[128 * 64];   // 16 KB, [row][64k], chunk c holds k-chunk c^(row&7)
    __shared__ ushortT Bs[128 * 64];   // 16 KB
    const int tid = threadIdx.x, l = tid & 63, wid = tid >> 6;
    const int wm = wid & 1, wn = wid >> 1;
    const int m0 = blockIdx.x * 128;
    const int n0 = blockIdx.y * 128;
    const int q = l >> 4, r = l & 15;
    const int swz = (l & 7) ^ ((l >> 3) & 7);

    f32x4 acc[4][4];
#pragma unroll
    for (int i = 0; i < 4; ++i)
#pragma unroll
        for (int j = 0; j < 4; ++j) acc[i][j] = (f32x4){0.f, 0.f, 0.f, 0.f};

    for (int kt = 0; kt < 256; kt += 64) {
#pragma unroll
        for (int i = 0; i < 4; ++i) {             // A: 16 issues of 1 KB
            int flat = wid * 4 + i;
            int row = flat * 8 + (l >> 3);
            llds16(Ac + (size_t)(m0 + row) * 256 + kt + swz * 8, &As[flat * 512]);
        }
#pragma unroll
        for (int i = 0; i < 4; ++i) {             // B: 16 issues of 1 KB
            int flat = wid * 4 + i;
            int row = flat * 8 + (l >> 3);
            llds16(WT1 + (size_t)(n0 + row) * 256 + kt + swz * 8, &Bs[flat * 512]);
        }
        __syncthreads();
#pragma unroll
        for (int ks = 0; ks < 64; ks += 32) {
            bf16x8 af[4], bfr[4];
            const int c0 = (ks >> 3) + q;
            const int cs = (c0 ^ (r & 7)) * 8;
#pragma unroll
            for (int mt = 0; mt < 4; ++mt)
                af[mt] = *(const bf16x8*)&As[(wm * 64 + mt * 16 + r) * 64 + cs];
#pragma unroll
            for (int nt = 0; nt < 4; ++nt)
                bfr[nt] = *(const bf16x8*)&Bs[(wn * 64 + nt * 16 + r) * 64 + cs];
#pragma unroll
            for (int mt = 0; mt < 4; ++mt)
#pragma unroll
                for (int nt = 0; nt < 4; ++nt)
                    acc[mt][nt] = __builtin_amdgcn_mfma_f32_16x16x32_bf16(
                        af[mt], bfr[nt], acc[mt][nt], 0, 0, 0);
        }
        __syncthreads();
    }
    // epilogue: +b1, relu, bf16 store (C/D: col=lane&15, row=(lane>>4)*4+reg)
#pragma unroll
    for (int mt = 0; mt < 4; ++mt) {
        int row0 = m0 + wm * 64 + mt * 16 + q * 4;
#pragma unroll
        for (int nt = 0; nt < 4; ++nt) {
            int colb = n0 + wn * 64 + nt * 16 + r;
            float bb = b1[colb];
#pragma unroll
            for (int j = 0; j < 4; ++j) {
                float v = fmaxf(acc[mt][nt][j] + bb, 0.f);
                h[(size_t)(row0 + j) * 256 + colb] = f2b(v);
            }
        }
    }
}

// ------------------------------------------------------------- layer-2 GEMM
// [y2|t] = h @ WT2^T; t += b2.  M=NNP, K=256, N=80.
// Block 128 rows x 80 cols, wave = 32 rows x 80 (acc 2x5 = 40 AGPR).
__global__ __launch_bounds__(256, 4) void k_gemm2(const ushortT* __restrict__ h,
                                                  const ushortT* __restrict__ WT2,
                                                  const float* __restrict__ b2,
                                                  ushortT* __restrict__ y2,
                                                  float* __restrict__ t) {
    __shared__ ushortT As[128 * 64];   // 16 KB
    __shared__ ushortT Bs[80 * 64];    // 10 KB
    const int tid = threadIdx.x, l = tid & 63, wid = tid >> 6;
    const int m0 = blockIdx.x * 128;
    const int q = l >> 4, r = l & 15;
    const int swz = (l & 7) ^ ((l >> 3) & 7);

    f32x4 acc[2][5];
#pragma unroll
    for (int i = 0; i < 2; ++i)
#pragma unroll
        for (int j = 0; j < 5; ++j) acc[i][j] = (f32x4){0.f, 0.f, 0.f, 0.f};

    for (int kt = 0; kt < 256; kt += 64) {
#pragma unroll
        for (int i = 0; i < 4; ++i) {             // A: 16 issues
            int flat = wid * 4 + i;
            int row = flat * 8 + (l >> 3);
            llds16(h + (size_t)(m0 + row) * 256 + kt + swz * 8, &As[flat * 512]);
        }
#pragma unroll
        for (int i = 0; i < 3; ++i) {             // B: 10 issues
            int flat = wid * 3 + i;
            if (flat < 10) {
                int row = flat * 8 + (l >> 3);
                llds16(WT2 + (size_t)row * 256 + kt + swz * 8, &Bs[flat * 512]);
            }
        }
        __syncthreads();
#pragma unroll
        for (int ks = 0; ks < 64; ks += 32) {
            bf16x8 af[2], bfr[5];
            const int c0 = (ks >> 3) + q;
            const int cs = (c0 ^ (r & 7)) * 8;
#pragma unroll
            for (int mt = 0; mt < 2; ++mt)
                af[mt] = *(const bf16x8*)&As[(wid * 32 + mt * 16 + r) * 64 + cs];
#pragma unroll
            for (int nt = 0; nt < 5; ++nt)
                bfr[nt] = *(const bf16x8*)&Bs[(nt * 16 + r) * 64 + cs];
#pragma unroll
            for (int mt = 0; mt < 2; ++mt)
#pragma unroll
                for (int nt = 0; nt < 5; ++nt)
                    acc[mt][nt] = __builtin_amdgcn_mfma_f32_16x16x32_bf16(
                        af[mt], bfr[nt], acc[mt][nt], 0, 0, 0);
        }
        __syncthreads();
    }
#pragma unroll
    for (int mt = 0; mt < 2; ++mt) {
        int row0 = m0 + wid * 32 + mt * 16 + q * 4;
#pragma unroll
        for (int nt = 0; nt < 5; ++nt) {
            int c = nt * 16 + r;
            float bb = (c >= 40) ? b2[c - 40] : 0.f;
#pragma unroll
            for (int j = 0; j < 4; ++j) {
                float v = acc[mt][nt][j];
                if (c < 40)
                    y2[(size_t)(row0 + j) * 40 + c] = f2b(v);
                else
                    t[(size_t)(row0 + j) * 40 + (c - 40)] = v + bb;
            }
        }
    }
}

// ------------------------------------------------------- mean aggregation 2
// out = mean_gather(y2 bf16) + t ; 4 edges in flight (16 lanes x ushort4).
__global__ __launch_bounds__(256) void k_agg2(const int* __restrict__ rp,
                                              const int* __restrict__ col,
                                              const ushortT* __restrict__ y2,
                                              const float* __restrict__ t,
                                              float* __restrict__ out) {
    int node = blockIdx.x * 4 + (threadIdx.x >> 6);
    int l = threadIdx.x & 63;
    if (node >= NN) return;
    int seg = l >> 4, dl = l & 15;                // dl<10 covers dims dl*4..+3
    int beg = rp[node], end = rp[node + 1];
    bool act = dl < 10;
    float a0 = 0.f, a1 = 0.f, a2 = 0.f, a3 = 0.f;
    for (int j = beg; j < end; j += 4) {
        int e = j + seg;
        if (e < end && act) {
            int c = col[e];
            ushort4 v = *(const ushort4*)(y2 + (size_t)c * 40 + dl * 4);
            a0 += b2f(v.x); a1 += b2f(v.y); a2 += b2f(v.z); a3 += b2f(v.w);
        }
    }
    a0 += __shfl_xor(a0, 16); a0 += __shfl_xor(a0, 32);
    a1 += __shfl_xor(a1, 16); a1 += __shfl_xor(a1, 32);
    a2 += __shfl_xor(a2, 16); a2 += __shfl_xor(a2, 32);
    a3 += __shfl_xor(a3, 16); a3 += __shfl_xor(a3, 32);
    if (seg == 0 && act) {
        float inv = 1.0f / fmaxf((float)(end - beg), 1.0f);
        size_t o = (size_t)node * 40 + dl * 4;
        float4 tv = *(const float4*)&t[o];
        float4 ov;
        ov.x = a0 * inv + tv.x;
        ov.y = a1 * inv + tv.y;
        ov.z = a2 * inv + tv.z;
        ov.w = a3 * inv + tv.w;
        *(float4*)&out[o] = ov;
    }
}

// ------------------------------------------------------------------- launch
extern "C" void kernel_launch(void* const* d_in, const int* in_sizes, int n_in,
                              void* d_out, int out_size, void* d_ws, size_t ws_size,
                              hipStream_t stream) {
    const float* x   = (const float*)d_in[0];
    const int*   ei  = (const int*)d_in[1];
    const int*   src = ei;
    const int*   dst = ei + NE;
    const float* W1l = (const float*)d_in[2];
    const float* b1  = (const float*)d_in[3];
    const float* W1r = (const float*)d_in[4];
    const float* W2l = (const float*)d_in[5];
    const float* b2  = (const float*)d_in[6];
    const float* W2r = (const float*)d_in[7];
    float* out = (float*)d_out;

    size_t off = 0;
    char* base = (char*)d_ws;
    auto alloc = [&](size_t bytes) -> void* {
        void* p = base + off;
        off += (bytes + 255) & ~(size_t)255;
        return p;
    };
    int*     deg  = (int*)alloc((size_t)NN * 4);
    int*     rp   = (int*)alloc((size_t)(NN + 1) * 4);
    int*     rank = (int*)alloc((size_t)NE * 4);
    int*     bsum = (int*)alloc(512 * 4);
    int*     col  = (int*)alloc((size_t)NE * 4);
    ushortT* Ac   = (ushortT*)alloc((size_t)NNP * 256 * 2);   // [agg|x] bf16
    ushortT* h    = (ushortT*)alloc((size_t)NNP * 256 * 2);
    ushortT* y2   = (ushortT*)alloc((size_t)NNP * 40 * 2);
    float*   t    = (float*)alloc((size_t)NNP * 40 * 4);
    ushortT* WT1  = (ushortT*)alloc(256 * 256 * 2);
    ushortT* WT2  = (ushortT*)alloc(80 * 256 * 2);

    hipMemsetAsync(deg, 0, (size_t)NN * 4, stream);
    k_rank<<<(NE + 255) / 256, 256, 0, stream>>>(dst, deg, rank);
    k_scan1<<<NB1, 256, 0, stream>>>(deg, rp, bsum);
    k_scan2<<<1, 512, 0, stream>>>(bsum);
    k_scan3<<<NB1, 256, 0, stream>>>(rp, bsum);
    k_fill<<<(NE + 255) / 256, 256, 0, stream>>>(src, dst, rank, rp, col);

    k_prep<<<(NN * 32) / 256, 256, 0, stream>>>(x, W1l, W1r, W2l, W2r, Ac, WT1, WT2);

    k_agg1<<<(NN + 3) / 4, 256, 0, stream>>>(rp, col, Ac);
    k_gemm1<<<dim3(NNP / 128, 2), 256, 0, stream>>>(Ac, WT1, b1, h);
    k_gemm2<<<NNP / 128, 256, 0, stream>>>(h, WT2, b2, y2, t);
    k_agg2<<<(NN + 3) / 4, 256, 0, stream>>>(rp, col, y2, t, out);
}

// Round 5
// 287.946 us; speedup vs baseline: 2.3838x; 1.0554x over previous
//
#include <hip/hip_runtime.h>
#include <hip/hip_bf16.h>

// GraphSAGE 2-layer, bf16 MFMA version.
//   L1: h   = relu([agg1|x] @ [W1l;W1r] + b1)   K=256, N=256, bf16 MFMA
//   L2: [y2|t] = h @ [W2l|W2r] (+b2 on t)       K=256, N=80,  bf16 MFMA
//   out = mean_gather(y2) + t
// R5: gather kernels prefetch col indices (1 coalesced load + __shfl bcast)
//     and keep 8 row-loads in flight (agg1 was latency-bound: 2.7 TB/s,
//     VALU 46%, nothing saturated). deg-zeroing folded into k_prep.

#define NN   100000
#define NNP  100096          // 782*128 = 391*256
#define NE   800000
#define NB1  391             // ceil(NN/256)

typedef unsigned short ushortT;
typedef __attribute__((ext_vector_type(8))) short bf16x8;
typedef __attribute__((ext_vector_type(4))) float f32x4;

__device__ __forceinline__ unsigned short f2b(float f) {
    unsigned u = __float_as_uint(f);
    return (unsigned short)((u + 0x7fffu + ((u >> 16) & 1u)) >> 16);
}
__device__ __forceinline__ float b2f(unsigned short v) {
    return __uint_as_float(((unsigned)v) << 16);
}
__device__ __forceinline__ void llds16(const unsigned short* g, unsigned short* s) {
    __builtin_amdgcn_global_load_lds(
        (const __attribute__((address_space(1))) void*)g,
        (__attribute__((address_space(3))) void*)s, 16, 0, 0);
}

// ---------------------------------------------------------------- CSR build
// degree + per-edge rank in one pass (atomicAdd's old value == rank)
__global__ __launch_bounds__(256) void k_rank(const int* __restrict__ dst,
                                              int* __restrict__ deg,
                                              int* __restrict__ rank) {
    int e = blockIdx.x * 256 + threadIdx.x;
    if (e < NE) rank[e] = atomicAdd(&deg[dst[e]], 1);
}

__global__ __launch_bounds__(256) void k_scan1(const int* __restrict__ deg,
                                               int* __restrict__ rp,
                                               int* __restrict__ bsum) {
    __shared__ int s[256];
    int t = threadIdx.x;
    int i = blockIdx.x * 256 + t;
    int v = (i < NN) ? deg[i] : 0;
    s[t] = v;
    __syncthreads();
    for (int off = 1; off < 256; off <<= 1) {
        int add = (t >= off) ? s[t - off] : 0;
        __syncthreads();
        s[t] += add;
        __syncthreads();
    }
    if (i < NN) rp[i] = s[t] - v;
    if (t == 255) bsum[blockIdx.x] = s[255];
}

__global__ __launch_bounds__(512) void k_scan2(int* __restrict__ bsum) {
    __shared__ int s[512];
    int t = threadIdx.x;
    int v = (t < NB1) ? bsum[t] : 0;
    s[t] = v;
    __syncthreads();
    for (int off = 1; off < 512; off <<= 1) {
        int add = (t >= off) ? s[t - off] : 0;
        __syncthreads();
        s[t] += add;
        __syncthreads();
    }
    if (t < NB1) bsum[t] = s[t] - v;
}

__global__ __launch_bounds__(256) void k_scan3(int* __restrict__ rp,
                                               const int* __restrict__ bsum) {
    int i = blockIdx.x * 256 + threadIdx.x;
    if (i < NN) rp[i] += bsum[blockIdx.x];
    if (i == 0) rp[NN] = NE;
}

// no atomic: position = rp[dst] + precomputed rank
__global__ __launch_bounds__(256) void k_fill(const int* __restrict__ src,
                                              const int* __restrict__ dst,
                                              const int* __restrict__ rank,
                                              const int* __restrict__ rp,
                                              int* __restrict__ col) {
    int e = blockIdx.x * 256 + threadIdx.x;
    if (e < NE) col[rp[dst[e]] + rank[e]] = src[e];
}

// ------------------------------------------------------------------- prep
// x fp32 -> bf16 into A_cat[:,128:256]; weights -> bf16 B^T; zero deg
__global__ __launch_bounds__(256) void k_prep(const float* __restrict__ x,
                                              const float* __restrict__ W1l,
                                              const float* __restrict__ W1r,
                                              const float* __restrict__ W2l,
                                              const float* __restrict__ W2r,
                                              ushortT* __restrict__ Ac,
                                              ushortT* __restrict__ WT1,
                                              ushortT* __restrict__ WT2,
                                              int* __restrict__ deg) {
    int t = blockIdx.x * 256 + threadIdx.x;       // NN*32 float4s
    int row = t >> 5, c4 = t & 31;
    float4 v = *(const float4*)&x[(size_t)row * 128 + c4 * 4];
    ushortT* p = Ac + (size_t)row * 256 + 128 + c4 * 4;
    p[0] = f2b(v.x); p[1] = f2b(v.y); p[2] = f2b(v.z); p[3] = f2b(v.w);

    if (t < NN) deg[t] = 0;
    if (t < 65536) {                              // WT1 [256n][256k]
        int n = t >> 8, k = t & 255;
        float w = (k < 128) ? W1l[(size_t)k * 256 + n] : W1r[(size_t)(k - 128) * 256 + n];
        WT1[t] = f2b(w);
    } else if (t < 65536 + 20480) {               // WT2 [80n][256k]
        int j = t - 65536;
        int n = j >> 8, k = j & 255;
        float w = (n < 40) ? W2l[(size_t)k * 40 + n] : W2r[(size_t)k * 40 + (n - 40)];
        WT2[j] = f2b(w);
    }
}

// ------------------------------------------------------- mean aggregation 1
// gather bf16 x rows (A_cat[:,128:]), write bf16 mean to A_cat[:,0:128].
// One wave per node. Col indices prefetched (coalesced) + __shfl broadcast;
// 8 row-loads in flight (4 segs x 2-deep unroll, 16 lanes x bf16x8 each).
__global__ __launch_bounds__(256) void k_agg1(const int* __restrict__ rp,
                                              const int* __restrict__ col,
                                              ushortT* __restrict__ Ac) {
    int node = blockIdx.x * 4 + (threadIdx.x >> 6);
    int l = threadIdx.x & 63;
    if (node >= NN) return;
    int seg = l >> 4, dl = l & 15;                // dl covers dims dl*8..dl*8+7
    int beg = rp[node];
    int deg = rp[node + 1] - beg;
    float a[8] = {0.f, 0.f, 0.f, 0.f, 0.f, 0.f, 0.f, 0.f};
    for (int base = 0; base < deg; base += 64) {
        int cnt = min(64, deg - base);
        int cv = col[beg + base + min(l, cnt - 1)];    // one coalesced load
        for (int j = 0; j < cnt; j += 8) {
            int e0 = j + seg, e1 = j + 4 + seg;
            int i0 = __shfl(cv, min(e0, cnt - 1));
            int i1 = __shfl(cv, min(e1, cnt - 1));
            bf16x8 v0 = {0, 0, 0, 0, 0, 0, 0, 0};
            bf16x8 v1 = {0, 0, 0, 0, 0, 0, 0, 0};
            if (e0 < cnt) v0 = *(const bf16x8*)(Ac + (size_t)i0 * 256 + 128 + dl * 8);
            if (e1 < cnt) v1 = *(const bf16x8*)(Ac + (size_t)i1 * 256 + 128 + dl * 8);
#pragma unroll
            for (int i = 0; i < 8; ++i)
                a[i] += b2f((unsigned short)v0[i]) + b2f((unsigned short)v1[i]);
        }
    }
#pragma unroll
    for (int i = 0; i < 8; ++i) {
        a[i] += __shfl_xor(a[i], 16);
        a[i] += __shfl_xor(a[i], 32);
    }
    if (seg == 0) {
        float inv = 1.0f / fmaxf((float)deg, 1.0f);
        bf16x8 o;
#pragma unroll
        for (int i = 0; i < 8; ++i) o[i] = (short)f2b(a[i] * inv);
        *(bf16x8*)(Ac + (size_t)node * 256 + dl * 8) = o;
    }
}

// ------------------------------------------------------------- layer-1 GEMM
// h = relu(A_cat @ WT1^T + b1).  M=NNP, K=256, N=256.
// Block 128x128, 4 waves 2x2, wave 64x64 (acc 4x4 = 64 AGPR), BK=64.
__global__ __launch_bounds__(256, 4) void k_gemm1(const ushortT* __restrict__ Ac,
                                                  const ushortT* __restrict__ WT1,
                                                  const float* __restrict__ b1,
                                                  ushortT* __restrict__ h) {
    __shared__ ushortT As[128 * 64];   // 16 KB, [row][64k], chunk c holds k-chunk c^(row&7)
    __shared__ ushortT Bs[128 * 64];   // 16 KB
    const int tid = threadIdx.x, l = tid & 63, wid = tid >> 6;
    const int wm = wid & 1, wn = wid >> 1;
    const int m0 = blockIdx.x * 128;
    const int n0 = blockIdx.y * 128;
    const int q = l >> 4, r = l & 15;
    const int swz = (l & 7) ^ ((l >> 3) & 7);

    f32x4 acc[4][4];
#pragma unroll
    for (int i = 0; i < 4; ++i)
#pragma unroll
        for (int j = 0; j < 4; ++j) acc[i][j] = (f32x4){0.f, 0.f, 0.f, 0.f};

    for (int kt = 0; kt < 256; kt += 64) {
#pragma unroll
        for (int i = 0; i < 4; ++i) {             // A: 16 issues of 1 KB
            int flat = wid * 4 + i;
            int row = flat * 8 + (l >> 3);
            llds16(Ac + (size_t)(m0 + row) * 256 + kt + swz * 8, &As[flat * 512]);
        }
#pragma unroll
        for (int i = 0; i < 4; ++i) {             // B: 16 issues of 1 KB
            int flat = wid * 4 + i;
            int row = flat * 8 + (l >> 3);
            llds16(WT1 + (size_t)(n0 + row) * 256 + kt + swz * 8, &Bs[flat * 512]);
        }
        __syncthreads();
#pragma unroll
        for (int ks = 0; ks < 64; ks += 32) {
            bf16x8 af[4], bfr[4];
            const int c0 = (ks >> 3) + q;
            const int cs = (c0 ^ (r & 7)) * 8;
#pragma unroll
            for (int mt = 0; mt < 4; ++mt)
                af[mt] = *(const bf16x8*)&As[(wm * 64 + mt * 16 + r) * 64 + cs];
#pragma unroll
            for (int nt = 0; nt < 4; ++nt)
                bfr[nt] = *(const bf16x8*)&Bs[(wn * 64 + nt * 16 + r) * 64 + cs];
#pragma unroll
            for (int mt = 0; mt < 4; ++mt)
#pragma unroll
                for (int nt = 0; nt < 4; ++nt)
                    acc[mt][nt] = __builtin_amdgcn_mfma_f32_16x16x32_bf16(
                        af[mt], bfr[nt], acc[mt][nt], 0, 0, 0);
        }
        __syncthreads();
    }
    // epilogue: +b1, relu, bf16 store (C/D: col=lane&15, row=(lane>>4)*4+reg)
#pragma unroll
    for (int mt = 0; mt < 4; ++mt) {
        int row0 = m0 + wm * 64 + mt * 16 + q * 4;
#pragma unroll
        for (int nt = 0; nt < 4; ++nt) {
            int colb = n0 + wn * 64 + nt * 16 + r;
            float bb = b1[colb];
#pragma unroll
            for (int j = 0; j < 4; ++j) {
                float v = fmaxf(acc[mt][nt][j] + bb, 0.f);
                h[(size_t)(row0 + j) * 256 + colb] = f2b(v);
            }
        }
    }
}

// ------------------------------------------------------------- layer-2 GEMM
// [y2|t] = h @ WT2^T; t += b2.  M=NNP, K=256, N=80.
// Block 128 rows x 80 cols, wave = 32 rows x 80 (acc 2x5 = 40 AGPR).
__global__ __launch_bounds__(256, 4) void k_gemm2(const ushortT* __restrict__ h,
                                                  const ushortT* __restrict__ WT2,
                                                  const float* __restrict__ b2,
                                                  ushortT* __restrict__ y2,
                                                  float* __restrict__ t) {
    __shared__ ushortT As[128 * 64];   // 16 KB
    __shared__ ushortT Bs[80 * 64];    // 10 KB
    const int tid = threadIdx.x, l = tid & 63, wid = tid >> 6;
    const int m0 = blockIdx.x * 128;
    const int q = l >> 4, r = l & 15;
    const int swz = (l & 7) ^ ((l >> 3) & 7);

    f32x4 acc[2][5];
#pragma unroll
    for (int i = 0; i < 2; ++i)
#pragma unroll
        for (int j = 0; j < 5; ++j) acc[i][j] = (f32x4){0.f, 0.f, 0.f, 0.f};

    for (int kt = 0; kt < 256; kt += 64) {
#pragma unroll
        for (int i = 0; i < 4; ++i) {             // A: 16 issues
            int flat = wid * 4 + i;
            int row = flat * 8 + (l >> 3);
            llds16(h + (size_t)(m0 + row) * 256 + kt + swz * 8, &As[flat * 512]);
        }
#pragma unroll
        for (int i = 0; i < 3; ++i) {             // B: 10 issues
            int flat = wid * 3 + i;
            if (flat < 10) {
                int row = flat * 8 + (l >> 3);
                llds16(WT2 + (size_t)row * 256 + kt + swz * 8, &Bs[flat * 512]);
            }
        }
        __syncthreads();
#pragma unroll
        for (int ks = 0; ks < 64; ks += 32) {
            bf16x8 af[2], bfr[5];
            const int c0 = (ks >> 3) + q;
            const int cs = (c0 ^ (r & 7)) * 8;
#pragma unroll
            for (int mt = 0; mt < 2; ++mt)
                af[mt] = *(const bf16x8*)&As[(wid * 32 + mt * 16 + r) * 64 + cs];
#pragma unroll
            for (int nt = 0; nt < 5; ++nt)
                bfr[nt] = *(const bf16x8*)&Bs[(nt * 16 + r) * 64 + cs];
#pragma unroll
            for (int mt = 0; mt < 2; ++mt)
#pragma unroll
                for (int nt = 0; nt < 5; ++nt)
                    acc[mt][nt] = __builtin_amdgcn_mfma_f32_16x16x32_bf16(
                        af[mt], bfr[nt], acc[mt][nt], 0, 0, 0);
        }
        __syncthreads();
    }
#pragma unroll
    for (int mt = 0; mt < 2; ++mt) {
        int row0 = m0 + wid * 32 + mt * 16 + q * 4;
#pragma unroll
        for (int nt = 0; nt < 5; ++nt) {
            int c = nt * 16 + r;
            float bb = (c >= 40) ? b2[c - 40] : 0.f;
#pragma unroll
            for (int j = 0; j < 4; ++j) {
                float v = acc[mt][nt][j];
                if (c < 40)
                    y2[(size_t)(row0 + j) * 40 + c] = f2b(v);
                else
                    t[(size_t)(row0 + j) * 40 + (c - 40)] = v + bb;
            }
        }
    }
}

// ------------------------------------------------------- mean aggregation 2
// out = mean_gather(y2 bf16) + t; col prefetch + 8 loads in flight.
__global__ __launch_bounds__(256) void k_agg2(const int* __restrict__ rp,
                                              const int* __restrict__ col,
                                              const ushortT* __restrict__ y2,
                                              const float* __restrict__ t,
                                              float* __restrict__ out) {
    int node = blockIdx.x * 4 + (threadIdx.x >> 6);
    int l = threadIdx.x & 63;
    if (node >= NN) return;
    int seg = l >> 4, dl = l & 15;                // dl<10 covers dims dl*4..+3
    int beg = rp[node];
    int deg = rp[node + 1] - beg;
    bool act = dl < 10;
    float a0 = 0.f, a1 = 0.f, a2 = 0.f, a3 = 0.f;
    for (int base = 0; base < deg; base += 64) {
        int cnt = min(64, deg - base);
        int cv = col[beg + base + min(l, cnt - 1)];
        for (int j = 0; j < cnt; j += 8) {
            int e0 = j + seg, e1 = j + 4 + seg;
            int i0 = __shfl(cv, min(e0, cnt - 1));
            int i1 = __shfl(cv, min(e1, cnt - 1));
            ushort4 v0 = {0, 0, 0, 0}, v1 = {0, 0, 0, 0};
            if (e0 < cnt && act) v0 = *(const ushort4*)(y2 + (size_t)i0 * 40 + dl * 4);
            if (e1 < cnt && act) v1 = *(const ushort4*)(y2 + (size_t)i1 * 40 + dl * 4);
            a0 += b2f(v0.x) + b2f(v1.x);
            a1 += b2f(v0.y) + b2f(v1.y);
            a2 += b2f(v0.z) + b2f(v1.z);
            a3 += b2f(v0.w) + b2f(v1.w);
        }
    }
    a0 += __shfl_xor(a0, 16); a0 += __shfl_xor(a0, 32);
    a1 += __shfl_xor(a1, 16); a1 += __shfl_xor(a1, 32);
    a2 += __shfl_xor(a2, 16); a2 += __shfl_xor(a2, 32);
    a3 += __shfl_xor(a3, 16); a3 += __shfl_xor(a3, 32);
    if (seg == 0 && act) {
        float inv = 1.0f / fmaxf((float)deg, 1.0f);
        size_t o = (size_t)node * 40 + dl * 4;
        float4 tv = *(const float4*)&t[o];
        float4 ov;
        ov.x = a0 * inv + tv.x;
        ov.y = a1 * inv + tv.y;
        ov.z = a2 * inv + tv.z;
        ov.w = a3 * inv + tv.w;
        *(float4*)&out[o] = ov;
    }
}

// ------------------------------------------------------------------- launch
extern "C" void kernel_launch(void* const* d_in, const int* in_sizes, int n_in,
                              void* d_out, int out_size, void* d_ws, size_t ws_size,
                              hipStream_t stream) {
    const float* x   = (const float*)d_in[0];
    const int*   ei  = (const int*)d_in[1];
    const int*   src = ei;
    const int*   dst = ei + NE;
    const float* W1l = (const float*)d_in[2];
    const float* b1  = (const float*)d_in[3];
    const float* W1r = (const float*)d_in[4];
    const float* W2l = (const float*)d_in[5];
    const float* b2  = (const float*)d_in[6];
    const float* W2r = (const float*)d_in[7];
    float* out = (float*)d_out;

    size_t off = 0;
    char* base = (char*)d_ws;
    auto alloc = [&](size_t bytes) -> void* {
        void* p = base + off;
        off += (bytes + 255) & ~(size_t)255;
        return p;
    };
    int*     deg  = (int*)alloc((size_t)NN * 4);
    int*     rp   = (int*)alloc((size_t)(NN + 1) * 4);
    int*     rank = (int*)alloc((size_t)NE * 4);
    int*     bsum = (int*)alloc(512 * 4);
    int*     col  = (int*)alloc((size_t)NE * 4);
    ushortT* Ac   = (ushortT*)alloc((size_t)NNP * 256 * 2);   // [agg|x] bf16
    ushortT* h    = (ushortT*)alloc((size_t)NNP * 256 * 2);
    ushortT* y2   = (ushortT*)alloc((size_t)NNP * 40 * 2);
    float*   t    = (float*)alloc((size_t)NNP * 40 * 4);
    ushortT* WT1  = (ushortT*)alloc(256 * 256 * 2);
    ushortT* WT2  = (ushortT*)alloc(80 * 256 * 2);

    k_prep<<<(NN * 32) / 256, 256, 0, stream>>>(x, W1l, W1r, W2l, W2r, Ac, WT1, WT2, deg);
    k_rank<<<(NE + 255) / 256, 256, 0, stream>>>(dst, deg, rank);
    k_scan1<<<NB1, 256, 0, stream>>>(deg, rp, bsum);
    k_scan2<<<1, 512, 0, stream>>>(bsum);
    k_scan3<<<NB1, 256, 0, stream>>>(rp, bsum);
    k_fill<<<(NE + 255) / 256, 256, 0, stream>>>(src, dst, rank, rp, col);

    k_agg1<<<(NN + 3) / 4, 256, 0, stream>>>(rp, col, Ac);
    k_gemm1<<<dim3(NNP / 128, 2), 256, 0, stream>>>(Ac, WT1, b1, h);
    k_gemm2<<<NNP / 128, 256, 0, stream>>>(h, WT2, b2, y2, t);
    k_agg2<<<(NN + 3) / 4, 256, 0, stream>>>(rp, col, y2, t, out);
}